// Round 1
// baseline (1198.280 us; speedup 1.0000x reference)
//
#include <hip/hip_runtime.h>

#define BATCH 256
#define TT 1024
#define DD 32
#define HH 64

__device__ __forceinline__ float fsig(float x) {
    float e = __builtin_amdgcn_exp2f(-1.4426950408889634f * x);
    return __builtin_amdgcn_rcpf(1.0f + e);
}
__device__ __forceinline__ float ftanh(float x) {
    // tanh(x) = 1 - 2/(1+exp(2x));  exp(2x) = exp2(2*log2(e)*x)
    float e = __builtin_amdgcn_exp2f(2.885390081777927f * x);
    return 1.0f - 2.0f * __builtin_amdgcn_rcpf(1.0f + e);
}

// thread layout: tid = j*8 + q*2 + hf
//   hf = tid & 1      (half of the dot dimension)
//   q  = (tid>>1)&3   (gate type: 0=i 1=f 2=g 3=o)
//   j  = tid>>3       (output index within H=64)
// gate row g = q*64 + j  (PyTorch gate order i,f,g,o)
__global__ __launch_bounds__(512, 2) void lstm2_fused(
    const float* __restrict__ x,
    const float* __restrict__ w_ih_l0, const float* __restrict__ w_hh_l0,
    const float* __restrict__ b_ih_l0, const float* __restrict__ b_hh_l0,
    const float* __restrict__ w_ih_l1, const float* __restrict__ w_hh_l1,
    const float* __restrict__ b_ih_l1, const float* __restrict__ b_hh_l1,
    const float* __restrict__ w_fc,   const float* __restrict__ b_fc,
    float* __restrict__ out)
{
    const int b   = blockIdx.x;
    const int tid = threadIdx.x;
    const int hf  = tid & 1;
    const int q   = (tid >> 1) & 3;
    const int j   = tid >> 3;
    const int g   = q * 64 + j;

    __shared__ float h1s[2][HH];
    __shared__ float h2s[2][HH];
    if (tid < HH) h2s[0][tid] = 0.0f;

    // ---- register-resident weight half-rows ----
    float wih0[16], whh0[32], wih1[32], whh1[32];
    {
        const float* p = w_ih_l0 + g * DD + hf * 16;
        #pragma unroll
        for (int k = 0; k < 16; ++k) wih0[k] = p[k];
        p = w_hh_l0 + g * HH + hf * 32;
        #pragma unroll
        for (int k = 0; k < 32; ++k) whh0[k] = p[k];
        p = w_ih_l1 + g * HH + hf * 32;
        #pragma unroll
        for (int k = 0; k < 32; ++k) wih1[k] = p[k];
        p = w_hh_l1 + g * HH + hf * 32;
        #pragma unroll
        for (int k = 0; k < 32; ++k) whh1[k] = p[k];
    }
    const float bias1 = b_ih_l0[g] + b_hh_l0[g];
    const float bias2 = b_ih_l1[g] + b_hh_l1[g];

    // h1 half held in registers (phase B loads it; next step's phase A reuses it)
    float h1reg[32];
    #pragma unroll
    for (int k = 0; k < 32; ++k) h1reg[k] = 0.0f;
    float c1 = 0.0f, c2 = 0.0f;

    // x for this batch element: row t = 8 float4; this thread's half = 4 float4
    const float4* xrow = (const float4*)(x + (size_t)b * TT * DD) + hf * 4;
    float xc[16];
    {
        float4 a0 = xrow[0], a1 = xrow[1], a2 = xrow[2], a3 = xrow[3];
        xc[0]=a0.x; xc[1]=a0.y; xc[2]=a0.z; xc[3]=a0.w;
        xc[4]=a1.x; xc[5]=a1.y; xc[6]=a1.z; xc[7]=a1.w;
        xc[8]=a2.x; xc[9]=a2.y; xc[10]=a2.z; xc[11]=a2.w;
        xc[12]=a3.x; xc[13]=a3.y; xc[14]=a3.z; xc[15]=a3.w;
    }

    __syncthreads();   // h2s[0] init visible before first phase B

    for (int t = 0; t < TT; ++t) {
        const int cur = t & 1;
        const int nxt = cur ^ 1;

        // prefetch next step's x (stays in bounds at t = T-1)
        const int tn = (t + 1 < TT) ? (t + 1) : t;
        const float4* xp = xrow + (size_t)tn * 8;
        float4 n0 = xp[0], n1 = xp[1], n2 = xp[2], n3 = xp[3];

        // ---------------- phase A: layer-1 gates ----------------
        float acc = 0.0f;
        #pragma unroll
        for (int k = 0; k < 16; ++k) acc += wih0[k] * xc[k];
        #pragma unroll
        for (int k = 0; k < 32; ++k) acc += whh0[k] * h1reg[k];
        acc += __shfl_xor(acc, 1);
        acc += bias1;

        float v = (q == 2) ? ftanh(acc) : fsig(acc);
        float vx2 = __shfl_xor(v, 2);
        float vx4 = __shfl_xor(v, 4);
        float vx6 = __shfl_xor(vx2, 4);
        float g00 = (q & 1) ? vx2 : v;
        float g01 = (q & 1) ? v   : vx2;
        float g10 = (q & 1) ? vx6 : vx4;
        float g11 = (q & 1) ? vx4 : vx6;
        float gi = (q & 2) ? g10 : g00;
        float gf = (q & 2) ? g11 : g01;
        float gG = (q & 2) ? g00 : g10;
        float gO = (q & 2) ? g01 : g11;

        c1 = gf * c1 + gi * gG;
        float h1v = gO * ftanh(c1);
        if ((tid & 7) == 0) h1s[nxt][j] = h1v;
        __syncthreads();

        // ---------------- phase B: layer-2 gates ----------------
        #pragma unroll
        for (int k = 0; k < 32; ++k) h1reg[k] = h1s[nxt][hf * 32 + k];

        float acc2 = 0.0f;
        #pragma unroll
        for (int k = 0; k < 32; ++k) acc2 += wih1[k] * h1reg[k];
        const float* h2p = &h2s[cur][hf * 32];
        #pragma unroll
        for (int k = 0; k < 32; ++k) acc2 += whh1[k] * h2p[k];
        acc2 += __shfl_xor(acc2, 1);
        acc2 += bias2;

        v   = (q == 2) ? ftanh(acc2) : fsig(acc2);
        vx2 = __shfl_xor(v, 2);
        vx4 = __shfl_xor(v, 4);
        vx6 = __shfl_xor(vx2, 4);
        g00 = (q & 1) ? vx2 : v;
        g01 = (q & 1) ? v   : vx2;
        g10 = (q & 1) ? vx6 : vx4;
        g11 = (q & 1) ? vx4 : vx6;
        gi = (q & 2) ? g10 : g00;
        gf = (q & 2) ? g11 : g01;
        gG = (q & 2) ? g00 : g10;
        gO = (q & 2) ? g01 : g11;

        c2 = gf * c2 + gi * gG;
        float h2v = gO * ftanh(c2);
        if ((tid & 7) == 0) h2s[nxt][j] = h2v;

        // commit prefetched x
        xc[0]=n0.x; xc[1]=n0.y; xc[2]=n0.z; xc[3]=n0.w;
        xc[4]=n1.x; xc[5]=n1.y; xc[6]=n1.z; xc[7]=n1.w;
        xc[8]=n2.x; xc[9]=n2.y; xc[10]=n2.z; xc[11]=n2.w;
        xc[12]=n3.x; xc[13]=n3.y; xc[14]=n3.z; xc[15]=n3.w;
        __syncthreads();
    }

    // final h2 is in h2s[0] (T even -> last nxt == 0); FC + sigmoid
    if (tid < HH) {
        float v = h2s[0][tid] * w_fc[tid];
        #pragma unroll
        for (int off = 32; off > 0; off >>= 1) v += __shfl_down(v, off);
        if (tid == 0) out[b] = fsig(v + b_fc[0]);
    }
}

extern "C" void kernel_launch(void* const* d_in, const int* in_sizes, int n_in,
                              void* d_out, int out_size, void* d_ws, size_t ws_size,
                              hipStream_t stream) {
    lstm2_fused<<<dim3(BATCH), dim3(512), 0, stream>>>(
        (const float*)d_in[0],
        (const float*)d_in[1], (const float*)d_in[2],
        (const float*)d_in[3], (const float*)d_in[4],
        (const float*)d_in[5], (const float*)d_in[6],
        (const float*)d_in[7], (const float*)d_in[8],
        (const float*)d_in[9], (const float*)d_in[10],
        (float*)d_out);
}

// Round 2
// 686.672 us; speedup vs baseline: 1.7451x; 1.7451x over previous
//
#include <hip/hip_runtime.h>

#define BATCH 256
#define TT 1024
#define DD 32
#define HH 64

__device__ __forceinline__ float fsig(float x) {
    float e = __builtin_amdgcn_exp2f(-1.4426950408889634f * x);
    return __builtin_amdgcn_rcpf(1.0f + e);
}

// quad_perm DPP move (VALU pipe, no LDS)
template<int CTRL>
__device__ __forceinline__ float fdpp(float x) {
    int r = __builtin_amdgcn_mov_dpp(__builtin_bit_cast(int, x), CTRL, 0xf, 0xf, true);
    return __builtin_bit_cast(float, r);
}

// Thread org: tid<256 -> layer1 group, tid>=256 -> layer2 group (runs 1 step behind).
// Within group: gtid = j*4+q ; q = dot-dim chunk AND gate type (i,f,g,o), j = output idx.
// Lane (j,q) accumulates partials P[m] for all 4 gates m of j over dim-chunk q,
// then a quad transpose-reduce leaves gate q's full sum in lane q.
__global__ __launch_bounds__(512, 2) void lstm2_pipe(
    const float* __restrict__ x,
    const float* __restrict__ w_ih_l0, const float* __restrict__ w_hh_l0,
    const float* __restrict__ b_ih_l0, const float* __restrict__ b_hh_l0,
    const float* __restrict__ w_ih_l1, const float* __restrict__ w_hh_l1,
    const float* __restrict__ b_ih_l1, const float* __restrict__ b_hh_l1,
    const float* __restrict__ w_fc,   const float* __restrict__ b_fc,
    float* __restrict__ out)
{
    const int b    = blockIdx.x;
    const int tid  = threadIdx.x;
    const bool isL1 = tid < 256;
    const int gtid = tid & 255;
    const int q    = gtid & 3;
    const int j    = gtid >> 2;
    const int g    = q * 64 + j;

    __shared__ float h1s[2][HH];
    __shared__ float h2s[2][HH];
    if (tid < HH) { h1s[0][tid]=0.f; h1s[1][tid]=0.f; h2s[0][tid]=0.f; h2s[1][tid]=0.f; }

    // per-lane activation constants: q==2 -> tanh(x)=2*sigma(2x)-1, else sigma(x)
    const float kk = (q == 2) ? -2.885390081777927f : -1.4426950408889634f;
    const float aa = (q == 2) ? 2.0f : 1.0f;
    const float bb = (q == 2) ? -1.0f : 0.0f;

    // shared register file for both groups' weights (same slots, different contents)
    float w[128];
    float bias;
    if (isL1) {
        #pragma unroll
        for (int m = 0; m < 4; ++m) {
            const float4* pih = (const float4*)(w_ih_l0 + (m*64 + j)*DD + q*8);
            *(float4*)&w[m*32+0] = pih[0];
            *(float4*)&w[m*32+4] = pih[1];
            const float4* phh = (const float4*)(w_hh_l0 + (m*64 + j)*HH + q*16);
            *(float4*)&w[m*32+8]  = phh[0];
            *(float4*)&w[m*32+12] = phh[1];
            *(float4*)&w[m*32+16] = phh[2];
            *(float4*)&w[m*32+20] = phh[3];
        }
        bias = b_ih_l0[g] + b_hh_l0[g];
    } else {
        #pragma unroll
        for (int m = 0; m < 4; ++m) {
            const float4* pih = (const float4*)(w_ih_l1 + (m*64 + j)*HH + q*16);
            *(float4*)&w[m*32+0]  = pih[0];
            *(float4*)&w[m*32+4]  = pih[1];
            *(float4*)&w[m*32+8]  = pih[2];
            *(float4*)&w[m*32+12] = pih[3];
            const float4* phh = (const float4*)(w_hh_l1 + (m*64 + j)*HH + q*16);
            *(float4*)&w[m*32+16] = phh[0];
            *(float4*)&w[m*32+20] = phh[1];
            *(float4*)&w[m*32+24] = phh[2];
            *(float4*)&w[m*32+28] = phh[3];
        }
        bias = b_ih_l1[g] + b_hh_l1[g];
    }

    float c = 0.0f;

    // L1 x prefetch: this lane's 8-float chunk of the current x row
    const float* xbase = x + (size_t)b * TT * DD + q * 8;
    float xc[8];
    if (isL1) {
        const float4* xp = (const float4*)xbase;
        *(float4*)&xc[0] = xp[0];
        *(float4*)&xc[4] = xp[1];
    }

    __syncthreads();

    for (int t = 0; t <= TT; ++t) {
        const int prev = (t + 1) & 1;   // (t-1)&1
        const int cur  = t & 1;
        if (isL1) {
            if (t < TT) {
                // prefetch next step's x
                const int tn = (t + 1 < TT) ? (t + 1) : t;
                const float4* xp = (const float4*)(xbase + (size_t)tn * DD);
                float4 n0 = xp[0], n1 = xp[1];

                float hq[16];
                const float4* hp = (const float4*)&h1s[prev][q*16];
                *(float4*)&hq[0]  = hp[0];
                *(float4*)&hq[4]  = hp[1];
                *(float4*)&hq[8]  = hp[2];
                *(float4*)&hq[12] = hp[3];

                float P[4] = {0.f, 0.f, 0.f, 0.f};
                #pragma unroll
                for (int m = 0; m < 4; ++m) {
                    #pragma unroll
                    for (int k = 0; k < 8; ++k)  P[m] += w[m*32 + k]     * xc[k];
                    #pragma unroll
                    for (int k = 0; k < 16; ++k) P[m] += w[m*32 + 8 + k] * hq[k];
                }
                // quad transpose-reduce: lane q <- sum over chunks of gate q
                float t0 = P[0] + fdpp<0xB1>(P[0]);
                float t1 = P[1] + fdpp<0xB1>(P[1]);
                float t2 = P[2] + fdpp<0xB1>(P[2]);
                float t3 = P[3] + fdpp<0xB1>(P[3]);
                float Alo = (q & 1) ? t1 : t0;
                float Ahi = (q & 1) ? t3 : t2;
                float ulo = Alo + fdpp<0x4E>(Alo);
                float uhi = Ahi + fdpp<0x4E>(Ahi);
                float S = ((q & 2) ? uhi : ulo) + bias;

                float e = __builtin_amdgcn_exp2f(kk * S);
                float v = aa * __builtin_amdgcn_rcpf(1.0f + e) + bb;

                float gi = fdpp<0x00>(v);
                float gf = fdpp<0x55>(v);
                float gg = fdpp<0xAA>(v);
                float go = fdpp<0xFF>(v);
                c = gf * c + gi * gg;
                float e2 = __builtin_amdgcn_exp2f(-2.885390081777927f * c);
                float th = 2.0f * __builtin_amdgcn_rcpf(1.0f + e2) - 1.0f;
                float hv = go * th;
                if (q == 0) h1s[cur][j] = hv;

                xc[0]=n0.x; xc[1]=n0.y; xc[2]=n0.z; xc[3]=n0.w;
                xc[4]=n1.x; xc[5]=n1.y; xc[6]=n1.z; xc[7]=n1.w;
            }
        } else {
            if (t > 0) {
                float h1q[16], h2q[16];
                const float4* p1 = (const float4*)&h1s[prev][q*16];
                const float4* p2 = (const float4*)&h2s[prev][q*16];
                *(float4*)&h1q[0]  = p1[0];
                *(float4*)&h1q[4]  = p1[1];
                *(float4*)&h1q[8]  = p1[2];
                *(float4*)&h1q[12] = p1[3];
                *(float4*)&h2q[0]  = p2[0];
                *(float4*)&h2q[4]  = p2[1];
                *(float4*)&h2q[8]  = p2[2];
                *(float4*)&h2q[12] = p2[3];

                float P[4] = {0.f, 0.f, 0.f, 0.f};
                #pragma unroll
                for (int m = 0; m < 4; ++m) {
                    #pragma unroll
                    for (int k = 0; k < 16; ++k) P[m] += w[m*32 + k]      * h1q[k];
                    #pragma unroll
                    for (int k = 0; k < 16; ++k) P[m] += w[m*32 + 16 + k] * h2q[k];
                }
                float t0 = P[0] + fdpp<0xB1>(P[0]);
                float t1 = P[1] + fdpp<0xB1>(P[1]);
                float t2 = P[2] + fdpp<0xB1>(P[2]);
                float t3 = P[3] + fdpp<0xB1>(P[3]);
                float Alo = (q & 1) ? t1 : t0;
                float Ahi = (q & 1) ? t3 : t2;
                float ulo = Alo + fdpp<0x4E>(Alo);
                float uhi = Ahi + fdpp<0x4E>(Ahi);
                float S = ((q & 2) ? uhi : ulo) + bias;

                float e = __builtin_amdgcn_exp2f(kk * S);
                float v = aa * __builtin_amdgcn_rcpf(1.0f + e) + bb;

                float gi = fdpp<0x00>(v);
                float gf = fdpp<0x55>(v);
                float gg = fdpp<0xAA>(v);
                float go = fdpp<0xFF>(v);
                c = gf * c + gi * gg;
                float e2 = __builtin_amdgcn_exp2f(-2.885390081777927f * c);
                float th = 2.0f * __builtin_amdgcn_rcpf(1.0f + e2) - 1.0f;
                float hv = go * th;
                if (q == 0) h2s[cur][j] = hv;
            }
        }
        __syncthreads();
    }

    // h2(T-1) sits in h2s[0] (written at iter t=1024). FC + sigmoid.
    if (tid < HH) {
        float v = h2s[0][tid] * w_fc[tid];
        #pragma unroll
        for (int off = 32; off > 0; off >>= 1) v += __shfl_down(v, off);
        if (tid == 0) out[b] = fsig(v + b_fc[0]);
    }
}

extern "C" void kernel_launch(void* const* d_in, const int* in_sizes, int n_in,
                              void* d_out, int out_size, void* d_ws, size_t ws_size,
                              hipStream_t stream) {
    lstm2_pipe<<<dim3(BATCH), dim3(512), 0, stream>>>(
        (const float*)d_in[0],
        (const float*)d_in[1], (const float*)d_in[2],
        (const float*)d_in[3], (const float*)d_in[4],
        (const float*)d_in[5], (const float*)d_in[6],
        (const float*)d_in[7], (const float*)d_in[8],
        (const float*)d_in[9], (const float*)d_in[10],
        (float*)d_out);
}

// Round 4
// 570.993 us; speedup vs baseline: 2.0986x; 1.2026x over previous
//
#include <hip/hip_runtime.h>

#define TT 1024
#define DD 32
#define HH 64

typedef __fp16 h2 __attribute__((ext_vector_type(2)));

__device__ __forceinline__ float fsig(float x) {
    float e = __builtin_amdgcn_exp2f(-1.4426950408889634f * x);
    return __builtin_amdgcn_rcpf(1.0f + e);
}

// quad_perm DPP move (VALU pipe, no LDS)
template<int CTRL>
__device__ __forceinline__ float fdpp(float x) {
    int r = __builtin_amdgcn_mov_dpp(__builtin_bit_cast(int, x), CTRL, 0xf, 0xf, true);
    return __builtin_bit_cast(float, r);
}

struct __attribute__((aligned(16))) H16 { h2 p[8]; };  // 16 f16 = 32 B

__device__ __forceinline__ void cvt4rtn(float4 f, h2* d) {
    d[0] = (h2){(__fp16)f.x, (__fp16)f.y};
    d[1] = (h2){(__fp16)f.z, (__fp16)f.w};
}

// Thread org (same as R2): tid<256 -> layer1, tid>=256 -> layer2 (1 step behind).
// gtid = j*4+q ; q = dot-dim chunk AND gate type; j = output idx.
__global__ __launch_bounds__(512, 1) void lstm2_dot2(
    const float* __restrict__ x,
    const float* __restrict__ w_ih_l0, const float* __restrict__ w_hh_l0,
    const float* __restrict__ b_ih_l0, const float* __restrict__ b_hh_l0,
    const float* __restrict__ w_ih_l1, const float* __restrict__ w_hh_l1,
    const float* __restrict__ b_ih_l1, const float* __restrict__ b_hh_l1,
    const float* __restrict__ w_fc,   const float* __restrict__ b_fc,
    float* __restrict__ out)
{
    const int b    = blockIdx.x;
    const int tid  = threadIdx.x;
    const bool isL1 = tid < 256;
    const int gtid = tid & 255;
    const int q    = gtid & 3;
    const int j    = gtid >> 2;
    const int g    = q * 64 + j;

    __shared__ __attribute__((aligned(32))) __fp16 h1s[2][HH];
    __shared__ __attribute__((aligned(32))) __fp16 h2sB[2][HH];
    if (tid < HH) {
        h1s[0][tid] = (__fp16)0.f; h1s[1][tid] = (__fp16)0.f;
        h2sB[0][tid] = (__fp16)0.f; h2sB[1][tid] = (__fp16)0.f;
    }

    // per-lane activation constants: q==2 -> tanh(x)=2*sigma(2x)-1, else sigma(x)
    const float kk = (q == 2) ? -2.885390081777927f : -1.4426950408889634f;
    const float aa = (q == 2) ? 2.0f : 1.0f;
    const float bb = (q == 2) ? -1.0f : 0.0f;

    // packed-f16 weights, register-resident.
    // L1: per gate m, stride 12: [0..3]=w_ih chunk (8), [4..11]=w_hh chunk (16)
    // L2: per gate m, stride 16: [0..7]=w_ih chunk (16), [8..15]=w_hh chunk (16)
    h2 wh[64];
    float bias;
    if (isL1) {
        #pragma unroll
        for (int m = 0; m < 4; ++m) {
            const float4* pih = (const float4*)(w_ih_l0 + (m*64 + j)*DD + q*8);
            cvt4rtn(pih[0], &wh[m*12 + 0]);
            cvt4rtn(pih[1], &wh[m*12 + 2]);
            const float4* phh = (const float4*)(w_hh_l0 + (m*64 + j)*HH + q*16);
            cvt4rtn(phh[0], &wh[m*12 + 4]);
            cvt4rtn(phh[1], &wh[m*12 + 6]);
            cvt4rtn(phh[2], &wh[m*12 + 8]);
            cvt4rtn(phh[3], &wh[m*12 + 10]);
        }
        bias = b_ih_l0[g] + b_hh_l0[g];
    } else {
        #pragma unroll
        for (int m = 0; m < 4; ++m) {
            const float4* pih = (const float4*)(w_ih_l1 + (m*64 + j)*HH + q*16);
            cvt4rtn(pih[0], &wh[m*16 + 0]);
            cvt4rtn(pih[1], &wh[m*16 + 2]);
            cvt4rtn(pih[2], &wh[m*16 + 4]);
            cvt4rtn(pih[3], &wh[m*16 + 6]);
            const float4* phh = (const float4*)(w_hh_l1 + (m*64 + j)*HH + q*16);
            cvt4rtn(phh[0], &wh[m*16 + 8]);
            cvt4rtn(phh[1], &wh[m*16 + 10]);
            cvt4rtn(phh[2], &wh[m*16 + 12]);
            cvt4rtn(phh[3], &wh[m*16 + 14]);
        }
        bias = b_ih_l1[g] + b_hh_l1[g];
    }

    float c = 0.0f;

    // L1 x prefetch: this lane's 8-float chunk of the current row, packed f16
    const float* xbase = x + (size_t)b * TT * DD + q * 8;
    h2 xh[4];
    if (isL1) {
        const float4* xp = (const float4*)xbase;
        float4 a0 = xp[0], a1 = xp[1];
        xh[0] = __builtin_amdgcn_cvt_pkrtz(a0.x, a0.y);
        xh[1] = __builtin_amdgcn_cvt_pkrtz(a0.z, a0.w);
        xh[2] = __builtin_amdgcn_cvt_pkrtz(a1.x, a1.y);
        xh[3] = __builtin_amdgcn_cvt_pkrtz(a1.z, a1.w);
    }

    __syncthreads();

    for (int t = 0; t <= TT; ++t) {
        const int prev = (t + 1) & 1;
        const int cur  = t & 1;
        if (isL1) {
            if (t < TT) {
                const int tn = (t + 1 < TT) ? (t + 1) : t;
                const float4* xp = (const float4*)(xbase + (size_t)tn * DD);
                float4 n0 = xp[0], n1 = xp[1];

                H16 hq = *(const H16*)&h1s[prev][q*16];

                float P[4];
                #pragma unroll
                for (int m = 0; m < 4; ++m) {
                    float s = 0.0f;
                    #pragma unroll
                    for (int k = 0; k < 4; ++k)
                        s = __builtin_amdgcn_fdot2(wh[m*12 + k], xh[k], s, false);
                    #pragma unroll
                    for (int k = 0; k < 8; ++k)
                        s = __builtin_amdgcn_fdot2(wh[m*12 + 4 + k], hq.p[k], s, false);
                    P[m] = s;
                }

                float t0 = P[0] + fdpp<0xB1>(P[0]);
                float t1 = P[1] + fdpp<0xB1>(P[1]);
                float t2 = P[2] + fdpp<0xB1>(P[2]);
                float t3 = P[3] + fdpp<0xB1>(P[3]);
                float Alo = (q & 1) ? t1 : t0;
                float Ahi = (q & 1) ? t3 : t2;
                float ulo = Alo + fdpp<0x4E>(Alo);
                float uhi = Ahi + fdpp<0x4E>(Ahi);
                float S = ((q & 2) ? uhi : ulo) + bias;

                float e = __builtin_amdgcn_exp2f(kk * S);
                float v = aa * __builtin_amdgcn_rcpf(1.0f + e) + bb;

                float gi = fdpp<0x00>(v);
                float gf = fdpp<0x55>(v);
                float gg = fdpp<0xAA>(v);
                float go = fdpp<0xFF>(v);
                c = gf * c + gi * gg;
                float e2 = __builtin_amdgcn_exp2f(-2.885390081777927f * c);
                float th = 2.0f * __builtin_amdgcn_rcpf(1.0f + e2) - 1.0f;
                float hv = go * th;
                if (q == 0) h1s[cur][j] = (__fp16)hv;

                xh[0] = __builtin_amdgcn_cvt_pkrtz(n0.x, n0.y);
                xh[1] = __builtin_amdgcn_cvt_pkrtz(n0.z, n0.w);
                xh[2] = __builtin_amdgcn_cvt_pkrtz(n1.x, n1.y);
                xh[3] = __builtin_amdgcn_cvt_pkrtz(n1.z, n1.w);
            }
        } else {
            if (t > 0) {
                H16 a1 = *(const H16*)&h1s[prev][q*16];
                H16 a2 = *(const H16*)&h2sB[prev][q*16];

                float P[4];
                #pragma unroll
                for (int m = 0; m < 4; ++m) {
                    float s = 0.0f;
                    #pragma unroll
                    for (int k = 0; k < 8; ++k)
                        s = __builtin_amdgcn_fdot2(wh[m*16 + k], a1.p[k], s, false);
                    #pragma unroll
                    for (int k = 0; k < 8; ++k)
                        s = __builtin_amdgcn_fdot2(wh[m*16 + 8 + k], a2.p[k], s, false);
                    P[m] = s;
                }

                float t0 = P[0] + fdpp<0xB1>(P[0]);
                float t1 = P[1] + fdpp<0xB1>(P[1]);
                float t2 = P[2] + fdpp<0xB1>(P[2]);
                float t3 = P[3] + fdpp<0xB1>(P[3]);
                float Alo = (q & 1) ? t1 : t0;
                float Ahi = (q & 1) ? t3 : t2;
                float ulo = Alo + fdpp<0x4E>(Alo);
                float uhi = Ahi + fdpp<0x4E>(Ahi);
                float S = ((q & 2) ? uhi : ulo) + bias;

                float e = __builtin_amdgcn_exp2f(kk * S);
                float v = aa * __builtin_amdgcn_rcpf(1.0f + e) + bb;

                float gi = fdpp<0x00>(v);
                float gf = fdpp<0x55>(v);
                float gg = fdpp<0xAA>(v);
                float go = fdpp<0xFF>(v);
                c = gf * c + gi * gg;
                float e2 = __builtin_amdgcn_exp2f(-2.885390081777927f * c);
                float th = 2.0f * __builtin_amdgcn_rcpf(1.0f + e2) - 1.0f;
                float hv = go * th;
                if (q == 0) h2sB[cur][j] = (__fp16)hv;
            }
        }
        __syncthreads();
    }

    // h2(T-1) is in h2sB[0] (written at iter t=1024, cur=0). FC + sigmoid.
    if (tid < HH) {
        float v = (float)h2sB[0][tid] * w_fc[tid];
        #pragma unroll
        for (int off = 32; off > 0; off >>= 1) v += __shfl_down(v, off);
        if (tid == 0) out[b] = fsig(v + b_fc[0]);
    }
}

extern "C" void kernel_launch(void* const* d_in, const int* in_sizes, int n_in,
                              void* d_out, int out_size, void* d_ws, size_t ws_size,
                              hipStream_t stream) {
    lstm2_dot2<<<dim3(256), dim3(512), 0, stream>>>(
        (const float*)d_in[0],
        (const float*)d_in[1], (const float*)d_in[2],
        (const float*)d_in[3], (const float*)d_in[4],
        (const float*)d_in[5], (const float*)d_in[6],
        (const float*)d_in[7], (const float*)d_in[8],
        (const float*)d_in[9], (const float*)d_in[10],
        (float*)d_out);
}